// Round 1
// baseline (181.526 us; speedup 1.0000x reference)
//
#include <hip/hip_runtime.h>

typedef unsigned short u16;
typedef unsigned int   u32;
typedef __attribute__((ext_vector_type(8))) short bf16x8;
typedef __attribute__((ext_vector_type(4))) float f32x4;

#define LROW 4096
#define NB   8192
#define PCOL 720
#define NPAD 768
#define HH   2048
#define INV_SQRT2F 0.70710678118654752440f

// ws layout: xbf (8192*4096 bf16 = 67108864 B) | G (768*4096 bf16 = 6291456 B) | std (8192 f32)
#define WS_XBF_BYTES ((size_t)67108864)
#define WS_G_BYTES   ((size_t)6291456)
#define WS_NEEDED    (WS_XBF_BYTES + WS_G_BYTES + (size_t)NB * 4)

__device__ __forceinline__ u16 f2bf(float f) {
    union { float f; u32 u; } v; v.f = f;
    u32 r = v.u + 0x7FFFu + ((v.u >> 16) & 1u);
    return (u16)(r >> 16);
}

// element-level XOR swizzle: keeps both contiguous-per-thread and strided LDS
// access <=2-way bank aliased (2-way is free on CDNA4)
#define SWZ(i) ((i) ^ (((i) >> 5) & 31))

// ---------------------------------------------------------------------------
// Kernel P: per-row moving-average (via prefix sum), std (ddof=1), x -> bf16
// ---------------------------------------------------------------------------
__global__ __launch_bounds__(256) void prep_rows(const float* __restrict__ x,
                                                 u16* __restrict__ xbf,
                                                 float* __restrict__ stdv) {
    __shared__ float S[LROW];
    __shared__ float wred[4];
    __shared__ float ends[2];
    __shared__ float rred[8];
    const int tid = threadIdx.x;
    const int lane = tid & 63, wv = tid >> 6;
    const size_t b = blockIdx.x;

    const float4* xr4 = (const float4*)(x + b * LROW);
    float4 q0 = xr4[tid * 4 + 0], q1 = xr4[tid * 4 + 1];
    float4 q2 = xr4[tid * 4 + 2], q3 = xr4[tid * 4 + 3];
    float r[16];
    r[0]=q0.x; r[1]=q0.y; r[2]=q0.z; r[3]=q0.w;
    r[4]=q1.x; r[5]=q1.y; r[6]=q1.z; r[7]=q1.w;
    r[8]=q2.x; r[9]=q2.y; r[10]=q2.z; r[11]=q2.w;
    r[12]=q3.x; r[13]=q3.y; r[14]=q3.z; r[15]=q3.w;

    float ps[16];
    float a = 0.f;
    #pragma unroll
    for (int k = 0; k < 16; ++k) { a += r[k]; ps[k] = a; }
    const float segsum = a;

    // wave-level inclusive scan of segment sums
    float v = segsum;
    #pragma unroll
    for (int off = 1; off < 64; off <<= 1) {
        float o = __shfl_up(v, off);
        if (lane >= off) v += o;
    }
    if (lane == 63) wred[wv] = v;
    if (tid == 0)   ends[0] = r[0];
    if (tid == 255) ends[1] = r[15];
    __syncthreads();

    float wbase = 0.f;
    #pragma unroll
    for (int w = 0; w < 4; ++w) if (w < wv) wbase += wred[w];
    const float ebase = wbase + v - segsum;  // exclusive prefix at element 16*tid

    #pragma unroll
    for (int k = 0; k < 16; ++k) {
        const int i = (tid << 4) + k;
        S[SWZ(i)] = ebase + ps[k];           // inclusive prefix S[i]
    }
    __syncthreads();

    const float x0 = ends[0], xl = ends[1];
    float s1 = 0.f, s2 = 0.f;
    u16 ob[16];
    #pragma unroll
    for (int k = 0; k < 16; ++k) {
        const int i = (tid << 4) + k;
        int h = i + 12; h = h > LROW - 1 ? LROW - 1 : h;
        float wsum = S[SWZ(h)];
        if (i >= 13) wsum -= S[SWZ(i - 13)];
        if (i < 12) wsum += (float)(12 - i) * x0;
        if (i > LROW - 13) wsum += (float)(i - (LROW - 13)) * xl;
        const float xi = r[k];
        const float rr = xi - wsum * 0.04f;   // res = x - trend
        s1 += rr; s2 += rr * rr;
        ob[k] = f2bf(xi);
    }

    uint4 o0, o1;
    o0.x = (u32)ob[0]  | ((u32)ob[1]  << 16);
    o0.y = (u32)ob[2]  | ((u32)ob[3]  << 16);
    o0.z = (u32)ob[4]  | ((u32)ob[5]  << 16);
    o0.w = (u32)ob[6]  | ((u32)ob[7]  << 16);
    o1.x = (u32)ob[8]  | ((u32)ob[9]  << 16);
    o1.y = (u32)ob[10] | ((u32)ob[11] << 16);
    o1.z = (u32)ob[12] | ((u32)ob[13] << 16);
    o1.w = (u32)ob[14] | ((u32)ob[15] << 16);
    uint4* op = (uint4*)(xbf + b * LROW + ((size_t)tid << 4));
    op[0] = o0; op[1] = o1;

    #pragma unroll
    for (int off = 32; off; off >>= 1) {
        s1 += __shfl_down(s1, off);
        s2 += __shfl_down(s2, off);
    }
    if (lane == 0) { rred[wv * 2] = s1; rred[wv * 2 + 1] = s2; }
    __syncthreads();
    if (tid == 0) {
        const float S1 = rred[0] + rred[2] + rred[4] + rred[6];
        const float S2 = rred[1] + rred[3] + rred[5] + rred[7];
        const float mean = S1 / (float)LROW;
        float var = (S2 - (float)LROW * mean * mean) / (float)(LROW - 1);
        var = var < 0.f ? 0.f : var;
        stdv[b] = sqrtf(var) + 1e-5f;
    }
}

// ---------------------------------------------------------------------------
// Kernel W: fold weights into G[p][l] (bf16), rows 720..767 zero-padded.
// G = (w - u)^T T  +  u  - (sqrt2*S_lo/L) * c,  u = Haar-expanded Wlo/Whi
// ---------------------------------------------------------------------------
__global__ __launch_bounds__(256) void prep_weights(const float* __restrict__ Wt,
                                                    const float* __restrict__ Wlo,
                                                    const float* __restrict__ Whi,
                                                    u16* __restrict__ Gm) {
    __shared__ float S[LROW];
    __shared__ float wred[4];
    __shared__ float sred[4];
    const int tid = threadIdx.x;
    const int lane = tid & 63, wv = tid >> 6;
    const int p = blockIdx.x;
    u16* grow = Gm + (size_t)p * LROW;
    if (p >= PCOL) {
        uint4 z; z.x = z.y = z.z = z.w = 0u;
        uint4* g4 = (uint4*)grow;
        for (int i = tid; i < LROW / 8; i += 256) g4[i] = z;
        return;
    }
    const float4* wt4 = (const float4*)(Wt + (size_t)p * LROW);
    float4 q0 = wt4[tid * 4 + 0], q1 = wt4[tid * 4 + 1];
    float4 q2 = wt4[tid * 4 + 2], q3 = wt4[tid * 4 + 3];
    const float4* lo4 = (const float4*)(Wlo + (size_t)p * HH);
    const float4* hi4 = (const float4*)(Whi + (size_t)p * HH);
    float4 a0 = lo4[tid * 2 + 0], a1 = lo4[tid * 2 + 1];
    float4 b0 = hi4[tid * 2 + 0], b1 = hi4[tid * 2 + 1];

    float w[16];
    w[0]=q0.x; w[1]=q0.y; w[2]=q0.z; w[3]=q0.w;
    w[4]=q1.x; w[5]=q1.y; w[6]=q1.z; w[7]=q1.w;
    w[8]=q2.x; w[9]=q2.y; w[10]=q2.z; w[11]=q2.w;
    w[12]=q3.x; w[13]=q3.y; w[14]=q3.z; w[15]=q3.w;
    float lv[8] = {a0.x,a0.y,a0.z,a0.w,a1.x,a1.y,a1.z,a1.w};
    float hv[8] = {b0.x,b0.y,b0.z,b0.w,b1.x,b1.y,b1.z,b1.w};

    float u[16], z_[16];
    float slo = 0.f;
    #pragma unroll
    for (int j = 0; j < 8; ++j) {
        u[2*j]   = (lv[j] + hv[j]) * INV_SQRT2F;
        u[2*j+1] = (lv[j] - hv[j]) * INV_SQRT2F;
        slo += lv[j];
    }
    #pragma unroll
    for (int k = 0; k < 16; ++k) z_[k] = w[k] - u[k];

    float ps[16];
    float a = 0.f;
    #pragma unroll
    for (int k = 0; k < 16; ++k) { a += z_[k]; ps[k] = a; }
    const float segsum = a;

    float v = segsum;
    #pragma unroll
    for (int off = 1; off < 64; off <<= 1) {
        float o = __shfl_up(v, off);
        if (lane >= off) v += o;
    }
    if (lane == 63) wred[wv] = v;
    #pragma unroll
    for (int off = 32; off; off >>= 1) slo += __shfl_down(slo, off);
    if (lane == 0) sred[wv] = slo;
    __syncthreads();

    float wbase = 0.f;
    #pragma unroll
    for (int ww = 0; ww < 4; ++ww) if (ww < wv) wbase += wred[ww];
    const float ebase = wbase + v - segsum;
    const float SLO = sred[0] + sred[1] + sred[2] + sred[3];

    #pragma unroll
    for (int k = 0; k < 16; ++k) {
        const int i = (tid << 4) + k;
        S[SWZ(i)] = ebase + ps[k];
    }
    __syncthreads();

    const float coef = -1.4142135623730951f * SLO / (float)LROW;
    u16 ob[16];
    #pragma unroll
    for (int k = 0; k < 16; ++k) {
        const int l = (tid << 4) + k;
        float zT;
        if (l == 0) {
            float acc = 0.f;
            for (int m = 0; m <= 12; ++m) acc += S[SWZ(m)];
            zT = acc * 0.04f;                      // sum_{i<=12}(13-i) z_i / 25
        } else if (l == LROW - 1) {
            float acc = 0.f;
            for (int m = 0; m <= 12; ++m) acc += S[SWZ(LROW - 2 - m)];
            zT = (13.f * S[SWZ(LROW - 1)] - acc) * 0.04f;
        } else {
            int h = l + 12; h = h > LROW - 1 ? LROW - 1 : h;
            float t_ = S[SWZ(h)];
            if (l >= 13) t_ -= S[SWZ(l - 13)];
            zT = t_ * 0.04f;                       // truncated window / 25
        }
        float c;
        const int dmin = l < (LROW - 1 - l) ? l : (LROW - 1 - l);
        if (dmin >= 12)      c = 0.f;
        else if (dmin == 0)  c = -66.f / 25.f;
        else                 c = (float)(12 - dmin) * 0.04f;
        ob[k] = f2bf(zT + u[k] + coef * c);
    }

    uint4 o0, o1;
    o0.x = (u32)ob[0]  | ((u32)ob[1]  << 16);
    o0.y = (u32)ob[2]  | ((u32)ob[3]  << 16);
    o0.z = (u32)ob[4]  | ((u32)ob[5]  << 16);
    o0.w = (u32)ob[6]  | ((u32)ob[7]  << 16);
    o1.x = (u32)ob[8]  | ((u32)ob[9]  << 16);
    o1.y = (u32)ob[10] | ((u32)ob[11] << 16);
    o1.z = (u32)ob[12] | ((u32)ob[13] << 16);
    o1.w = (u32)ob[14] | ((u32)ob[15] << 16);
    uint4* op = (uint4*)(grow + ((size_t)tid << 4));
    op[0] = o0; op[1] = o1;
}

// ---------------------------------------------------------------------------
// Kernel E: out[b][p] = b_trend[p] + std[b]*(b_lo[p]+b_hi[p])
// ---------------------------------------------------------------------------
__global__ __launch_bounds__(256) void bias_init(const float* __restrict__ bt,
                                                 const float* __restrict__ bl,
                                                 const float* __restrict__ bh,
                                                 const float* __restrict__ stdv,
                                                 float* __restrict__ out) {
    const int pc = blockIdx.x * 256 + threadIdx.x;
    const int b = blockIdx.y;
    if (pc < PCOL)
        out[(size_t)b * PCOL + pc] = bt[pc] + stdv[b] * (bl[pc] + bh[pc]);
}

// ---------------------------------------------------------------------------
// Kernel G: out += xbf @ G^T   (M=8192, N=768 pad, K=4096), bf16 MFMA,
// 128x128 tile, 4 waves 2x2, global_load_lds w=16, split-K=2 via atomicAdd
// ---------------------------------------------------------------------------
#define BKg 32
typedef __attribute__((address_space(1))) void gvoid;
typedef __attribute__((address_space(3))) void lvoid;
#define GLD16(g, l) __builtin_amdgcn_global_load_lds((gvoid*)(g), (lvoid*)(l), 16, 0, 0)

__global__ __launch_bounds__(256) void gemm_splitk(const u16* __restrict__ Abf,
                                                   const u16* __restrict__ Gbf,
                                                   float* __restrict__ out) {
    __shared__ __align__(16) u16 As[128 * BKg];
    __shared__ __align__(16) u16 Bs[128 * BKg];
    const int tid = threadIdx.x;
    const int lane = tid & 63, wid = tid >> 6;
    const int m0 = blockIdx.y * 128;
    const int n0 = blockIdx.x * 128;
    const int kbeg = blockIdx.z * (LROW / 2);

    // staging: LDS linear [row][BKg], 64B rows; lane l of wave w writes
    // bytes [i*4096 + w*1024 + l*16); global source matches that linear order
    const int o0 = wid * 1024 + lane * 16;
    const char* gA[2]; const char* gB[2];
    u16* lA[2]; u16* lB[2];
    #pragma unroll
    for (int i = 0; i < 2; ++i) {
        const int o = o0 + i * 4096;
        gA[i] = (const char*)Abf + (((size_t)(m0 + (o >> 6))) << 13) + (o & 63) + ((size_t)kbeg << 1);
        gB[i] = (const char*)Gbf + (((size_t)(n0 + (o >> 6))) << 13) + (o & 63) + ((size_t)kbeg << 1);
        lA[i] = As + i * 2048 + wid * 512;   // wave-uniform LDS base (HW adds lane*16B)
        lB[i] = Bs + i * 2048 + wid * 512;
    }

    const int wm = wid >> 1, wn = wid & 1;
    const u16* aptr = As + (wm * 64 + (lane & 15)) * BKg + ((lane >> 4) << 3);
    const u16* bptr = Bs + (wn * 64 + (lane & 15)) * BKg + ((lane >> 4) << 3);

    f32x4 acc[4][4] = {};

    const int ksteps = (LROW / 2) / BKg;   // 64
    for (int kt = 0; kt < ksteps; ++kt) {
        const int koff = kt * (BKg * 2);
        GLD16(gA[0] + koff, lA[0]);
        GLD16(gA[1] + koff, lA[1]);
        GLD16(gB[0] + koff, lB[0]);
        GLD16(gB[1] + koff, lB[1]);
        __syncthreads();

        bf16x8 af[4], bfr[4];
        #pragma unroll
        for (int m = 0; m < 4; ++m) af[m]  = *(const bf16x8*)(aptr + m * 16 * BKg);
        #pragma unroll
        for (int n = 0; n < 4; ++n) bfr[n] = *(const bf16x8*)(bptr + n * 16 * BKg);
        #pragma unroll
        for (int m = 0; m < 4; ++m)
            #pragma unroll
            for (int n = 0; n < 4; ++n)
                acc[m][n] = __builtin_amdgcn_mfma_f32_16x16x32_bf16(af[m], bfr[n], acc[m][n], 0, 0, 0);
        __syncthreads();
    }

    // epilogue: C/D layout col=lane&15, row=(lane>>4)*4+j
    const int crow0 = m0 + wm * 64 + ((lane >> 4) << 2);
    const int ccol0 = n0 + wn * 64 + (lane & 15);
    #pragma unroll
    for (int m = 0; m < 4; ++m)
        #pragma unroll
        for (int n = 0; n < 4; ++n) {
            const int col = ccol0 + n * 16;
            if (col < PCOL) {
                float* orow = out + (size_t)(crow0 + m * 16) * PCOL + col;
                #pragma unroll
                for (int j = 0; j < 4; ++j)
                    atomicAdd(orow + (size_t)j * PCOL, acc[m][n][j]);
            }
        }
}

// ---------------------------------------------------------------------------
extern "C" void kernel_launch(void* const* d_in, const int* in_sizes, int n_in,
                              void* d_out, int out_size, void* d_ws, size_t ws_size,
                              hipStream_t stream) {
    (void)in_sizes; (void)n_in; (void)out_size;
    if (ws_size < WS_NEEDED) return;  // fail visibly (poisoned out) rather than corrupt

    const float* x  = (const float*)d_in[0];
    const float* Wt = (const float*)d_in[1];
    const float* bt = (const float*)d_in[2];
    const float* Wl = (const float*)d_in[3];
    const float* bl = (const float*)d_in[4];
    const float* Wh = (const float*)d_in[5];
    const float* bh = (const float*)d_in[6];
    float* out = (float*)d_out;

    char* ws = (char*)d_ws;
    u16*   xbf = (u16*)ws;
    u16*   Gm  = (u16*)(ws + WS_XBF_BYTES);
    float* sd  = (float*)(ws + WS_XBF_BYTES + WS_G_BYTES);

    prep_rows<<<NB, 256, 0, stream>>>(x, xbf, sd);
    prep_weights<<<NPAD, 256, 0, stream>>>(Wt, Wl, Wh, Gm);
    bias_init<<<dim3(3, NB), 256, 0, stream>>>(bt, bl, bh, sd, out);
    gemm_splitk<<<dim3(6, 64, 2), 256, 0, stream>>>(xbf, Gm, out);
}

// Round 2
// 160.721 us; speedup vs baseline: 1.1294x; 1.1294x over previous
//
#include <hip/hip_runtime.h>

typedef unsigned short u16;
typedef unsigned int   u32;
typedef __attribute__((ext_vector_type(8))) short bf16x8;
typedef __attribute__((ext_vector_type(4))) float f32x4;

#define LROW 4096
#define NB   8192
#define PCOL 720
#define NPAD 768
#define HH   2048
#define INV_SQRT2F 0.70710678118654752440f

// ws layout: xbf | G | std | partial(optional)
#define WS_XBF_BYTES ((size_t)67108864)           // 8192*4096*2
#define WS_G_BYTES   ((size_t)6291456)            // 768*4096*2
#define WS_STD_BYTES ((size_t)(NB * 4))
#define WS_MIN       (WS_XBF_BYTES + WS_G_BYTES + WS_STD_BYTES)
#define WS_PART_BYTES ((size_t)2 * NB * NPAD * 4) // 50331648
#define WS_FULL      (WS_MIN + WS_PART_BYTES)

__device__ __forceinline__ u16 f2bf(float f) {
    union { float f; u32 u; } v; v.f = f;
    u32 r = v.u + 0x7FFFu + ((v.u >> 16) & 1u);
    return (u16)(r >> 16);
}

#define SWZ(i) ((i) ^ (((i) >> 5) & 31))

// ---------------------------------------------------------------------------
// Kernel P: per-row moving-average (via prefix sum), std (ddof=1), x -> bf16
// ---------------------------------------------------------------------------
__global__ __launch_bounds__(256) void prep_rows(const float* __restrict__ x,
                                                 u16* __restrict__ xbf,
                                                 float* __restrict__ stdv) {
    __shared__ float S[LROW];
    __shared__ float wred[4];
    __shared__ float ends[2];
    __shared__ float rred[8];
    const int tid = threadIdx.x;
    const int lane = tid & 63, wv = tid >> 6;
    const size_t b = blockIdx.x;

    const float4* xr4 = (const float4*)(x + b * LROW);
    float4 q0 = xr4[tid * 4 + 0], q1 = xr4[tid * 4 + 1];
    float4 q2 = xr4[tid * 4 + 2], q3 = xr4[tid * 4 + 3];
    float r[16];
    r[0]=q0.x; r[1]=q0.y; r[2]=q0.z; r[3]=q0.w;
    r[4]=q1.x; r[5]=q1.y; r[6]=q1.z; r[7]=q1.w;
    r[8]=q2.x; r[9]=q2.y; r[10]=q2.z; r[11]=q2.w;
    r[12]=q3.x; r[13]=q3.y; r[14]=q3.z; r[15]=q3.w;

    float ps[16];
    float a = 0.f;
    #pragma unroll
    for (int k = 0; k < 16; ++k) { a += r[k]; ps[k] = a; }
    const float segsum = a;

    float v = segsum;
    #pragma unroll
    for (int off = 1; off < 64; off <<= 1) {
        float o = __shfl_up(v, off);
        if (lane >= off) v += o;
    }
    if (lane == 63) wred[wv] = v;
    if (tid == 0)   ends[0] = r[0];
    if (tid == 255) ends[1] = r[15];
    __syncthreads();

    float wbase = 0.f;
    #pragma unroll
    for (int w = 0; w < 4; ++w) if (w < wv) wbase += wred[w];
    const float ebase = wbase + v - segsum;

    #pragma unroll
    for (int k = 0; k < 16; ++k) {
        const int i = (tid << 4) + k;
        S[SWZ(i)] = ebase + ps[k];
    }
    __syncthreads();

    const float x0 = ends[0], xl = ends[1];
    float s1 = 0.f, s2 = 0.f;
    u16 ob[16];
    #pragma unroll
    for (int k = 0; k < 16; ++k) {
        const int i = (tid << 4) + k;
        int h = i + 12; h = h > LROW - 1 ? LROW - 1 : h;
        float wsum = S[SWZ(h)];
        if (i >= 13) wsum -= S[SWZ(i - 13)];
        if (i < 12) wsum += (float)(12 - i) * x0;
        if (i > LROW - 13) wsum += (float)(i - (LROW - 13)) * xl;
        const float xi = r[k];
        const float rr = xi - wsum * 0.04f;
        s1 += rr; s2 += rr * rr;
        ob[k] = f2bf(xi);
    }

    uint4 o0, o1;
    o0.x = (u32)ob[0]  | ((u32)ob[1]  << 16);
    o0.y = (u32)ob[2]  | ((u32)ob[3]  << 16);
    o0.z = (u32)ob[4]  | ((u32)ob[5]  << 16);
    o0.w = (u32)ob[6]  | ((u32)ob[7]  << 16);
    o1.x = (u32)ob[8]  | ((u32)ob[9]  << 16);
    o1.y = (u32)ob[10] | ((u32)ob[11] << 16);
    o1.z = (u32)ob[12] | ((u32)ob[13] << 16);
    o1.w = (u32)ob[14] | ((u32)ob[15] << 16);
    uint4* op = (uint4*)(xbf + b * LROW + ((size_t)tid << 4));
    op[0] = o0; op[1] = o1;

    #pragma unroll
    for (int off = 32; off; off >>= 1) {
        s1 += __shfl_down(s1, off);
        s2 += __shfl_down(s2, off);
    }
    if (lane == 0) { rred[wv * 2] = s1; rred[wv * 2 + 1] = s2; }
    __syncthreads();
    if (tid == 0) {
        const float S1 = rred[0] + rred[2] + rred[4] + rred[6];
        const float S2 = rred[1] + rred[3] + rred[5] + rred[7];
        const float mean = S1 / (float)LROW;
        float var = (S2 - (float)LROW * mean * mean) / (float)(LROW - 1);
        var = var < 0.f ? 0.f : var;
        stdv[b] = sqrtf(var) + 1e-5f;
    }
}

// ---------------------------------------------------------------------------
// Kernel W: fold weights into G[p][l] (bf16), rows 720..767 zero-padded.
// ---------------------------------------------------------------------------
__global__ __launch_bounds__(256) void prep_weights(const float* __restrict__ Wt,
                                                    const float* __restrict__ Wlo,
                                                    const float* __restrict__ Whi,
                                                    u16* __restrict__ Gm) {
    __shared__ float S[LROW];
    __shared__ float wred[4];
    __shared__ float sred[4];
    const int tid = threadIdx.x;
    const int lane = tid & 63, wv = tid >> 6;
    const int p = blockIdx.x;
    u16* grow = Gm + (size_t)p * LROW;
    if (p >= PCOL) {
        uint4 z; z.x = z.y = z.z = z.w = 0u;
        uint4* g4 = (uint4*)grow;
        for (int i = tid; i < LROW / 8; i += 256) g4[i] = z;
        return;
    }
    const float4* wt4 = (const float4*)(Wt + (size_t)p * LROW);
    float4 q0 = wt4[tid * 4 + 0], q1 = wt4[tid * 4 + 1];
    float4 q2 = wt4[tid * 4 + 2], q3 = wt4[tid * 4 + 3];
    const float4* lo4 = (const float4*)(Wlo + (size_t)p * HH);
    const float4* hi4 = (const float4*)(Whi + (size_t)p * HH);
    float4 a0 = lo4[tid * 2 + 0], a1 = lo4[tid * 2 + 1];
    float4 b0 = hi4[tid * 2 + 0], b1 = hi4[tid * 2 + 1];

    float w[16];
    w[0]=q0.x; w[1]=q0.y; w[2]=q0.z; w[3]=q0.w;
    w[4]=q1.x; w[5]=q1.y; w[6]=q1.z; w[7]=q1.w;
    w[8]=q2.x; w[9]=q2.y; w[10]=q2.z; w[11]=q2.w;
    w[12]=q3.x; w[13]=q3.y; w[14]=q3.z; w[15]=q3.w;
    float lv[8] = {a0.x,a0.y,a0.z,a0.w,a1.x,a1.y,a1.z,a1.w};
    float hv[8] = {b0.x,b0.y,b0.z,b0.w,b1.x,b1.y,b1.z,b1.w};

    float u[16], z_[16];
    float slo = 0.f;
    #pragma unroll
    for (int j = 0; j < 8; ++j) {
        u[2*j]   = (lv[j] + hv[j]) * INV_SQRT2F;
        u[2*j+1] = (lv[j] - hv[j]) * INV_SQRT2F;
        slo += lv[j];
    }
    #pragma unroll
    for (int k = 0; k < 16; ++k) z_[k] = w[k] - u[k];

    float ps[16];
    float a = 0.f;
    #pragma unroll
    for (int k = 0; k < 16; ++k) { a += z_[k]; ps[k] = a; }
    const float segsum = a;

    float v = segsum;
    #pragma unroll
    for (int off = 1; off < 64; off <<= 1) {
        float o = __shfl_up(v, off);
        if (lane >= off) v += o;
    }
    if (lane == 63) wred[wv] = v;
    #pragma unroll
    for (int off = 32; off; off >>= 1) slo += __shfl_down(slo, off);
    if (lane == 0) sred[wv] = slo;
    __syncthreads();

    float wbase = 0.f;
    #pragma unroll
    for (int ww = 0; ww < 4; ++ww) if (ww < wv) wbase += wred[ww];
    const float ebase = wbase + v - segsum;
    const float SLO = sred[0] + sred[1] + sred[2] + sred[3];

    #pragma unroll
    for (int k = 0; k < 16; ++k) {
        const int i = (tid << 4) + k;
        S[SWZ(i)] = ebase + ps[k];
    }
    __syncthreads();

    const float coef = -1.4142135623730951f * SLO / (float)LROW;
    u16 ob[16];
    #pragma unroll
    for (int k = 0; k < 16; ++k) {
        const int l = (tid << 4) + k;
        float zT;
        if (l == 0) {
            float acc = 0.f;
            for (int m = 0; m <= 12; ++m) acc += S[SWZ(m)];
            zT = acc * 0.04f;
        } else if (l == LROW - 1) {
            float acc = 0.f;
            for (int m = 0; m <= 12; ++m) acc += S[SWZ(LROW - 2 - m)];
            zT = (13.f * S[SWZ(LROW - 1)] - acc) * 0.04f;
        } else {
            int h = l + 12; h = h > LROW - 1 ? LROW - 1 : h;
            float t_ = S[SWZ(h)];
            if (l >= 13) t_ -= S[SWZ(l - 13)];
            zT = t_ * 0.04f;
        }
        float c;
        const int dmin = l < (LROW - 1 - l) ? l : (LROW - 1 - l);
        if (dmin >= 12)      c = 0.f;
        else if (dmin == 0)  c = -66.f / 25.f;
        else                 c = (float)(12 - dmin) * 0.04f;
        ob[k] = f2bf(zT + u[k] + coef * c);
    }

    uint4 o0, o1;
    o0.x = (u32)ob[0]  | ((u32)ob[1]  << 16);
    o0.y = (u32)ob[2]  | ((u32)ob[3]  << 16);
    o0.z = (u32)ob[4]  | ((u32)ob[5]  << 16);
    o0.w = (u32)ob[6]  | ((u32)ob[7]  << 16);
    o1.x = (u32)ob[8]  | ((u32)ob[9]  << 16);
    o1.y = (u32)ob[10] | ((u32)ob[11] << 16);
    o1.z = (u32)ob[12] | ((u32)ob[13] << 16);
    o1.w = (u32)ob[14] | ((u32)ob[15] << 16);
    uint4* op = (uint4*)(grow + ((size_t)tid << 4));
    op[0] = o0; op[1] = o1;
}

// ---------------------------------------------------------------------------
// Kernel E (fallback path only): out[b][p] = bt[p] + std[b]*(bl[p]+bh[p])
// ---------------------------------------------------------------------------
__global__ __launch_bounds__(256) void bias_init(const float* __restrict__ bt,
                                                 const float* __restrict__ bl,
                                                 const float* __restrict__ bh,
                                                 const float* __restrict__ stdv,
                                                 float* __restrict__ out) {
    const int pc = blockIdx.x * 256 + threadIdx.x;
    const int b = blockIdx.y;
    if (pc < PCOL)
        out[(size_t)b * PCOL + pc] = bt[pc] + stdv[b] * (bl[pc] + bh[pc]);
}

// ---------------------------------------------------------------------------
// Kernel G: split-K=2 bf16 MFMA GEMM, 128x128 tile, XCD-chunked swizzle.
// ATOMIC=0: plain stores to partial[z][8192][768]; ATOMIC=1: atomicAdd to out.
// ---------------------------------------------------------------------------
#define BKg 32
typedef __attribute__((address_space(1))) void gvoid;
typedef __attribute__((address_space(3))) void lvoid;
#define GLD16(g, l) __builtin_amdgcn_global_load_lds((gvoid*)(g), (lvoid*)(l), 16, 0, 0)

template <int ATOMIC>
__global__ __launch_bounds__(256) void gemm_splitk(const u16* __restrict__ Abf,
                                                   const u16* __restrict__ Gbf,
                                                   float* __restrict__ dst) {
    __shared__ __align__(16) u16 As[128 * BKg];
    __shared__ __align__(16) u16 Bs[128 * BKg];
    const int tid = threadIdx.x;
    const int lane = tid & 63, wid = tid >> 6;

    // XCD-chunked bijective swizzle: 768 blocks = 8 XCDs x 96.
    // Within a chunk, n varies fastest -> 6 n-blocks of one m-tile share L2.
    const int orig = blockIdx.x;
    const int lin  = (orig & 7) * 96 + (orig >> 3);
    const int bx   = lin % 6;            // n-tile
    const int rem  = lin / 6;
    const int by   = rem & 63;           // m-tile
    const int bz   = rem >> 6;           // k-half
    const int m0 = by * 128;
    const int n0 = bx * 128;
    const int kbeg = bz * (LROW / 2);

    const int o0 = wid * 1024 + lane * 16;
    const char* gA[2]; const char* gB[2];
    u16* lA[2]; u16* lB[2];
    #pragma unroll
    for (int i = 0; i < 2; ++i) {
        const int o = o0 + i * 4096;
        gA[i] = (const char*)Abf + (((size_t)(m0 + (o >> 6))) << 13) + (o & 63) + ((size_t)kbeg << 1);
        gB[i] = (const char*)Gbf + (((size_t)(n0 + (o >> 6))) << 13) + (o & 63) + ((size_t)kbeg << 1);
        lA[i] = As + i * 2048 + wid * 512;
        lB[i] = Bs + i * 2048 + wid * 512;
    }

    const int wm = wid >> 1, wn = wid & 1;
    const u16* aptr = As + (wm * 64 + (lane & 15)) * BKg + ((lane >> 4) << 3);
    const u16* bptr = Bs + (wn * 64 + (lane & 15)) * BKg + ((lane >> 4) << 3);

    f32x4 acc[4][4] = {};

    const int ksteps = (LROW / 2) / BKg;   // 64
    for (int kt = 0; kt < ksteps; ++kt) {
        const int koff = kt * (BKg * 2);
        GLD16(gA[0] + koff, lA[0]);
        GLD16(gA[1] + koff, lA[1]);
        GLD16(gB[0] + koff, lB[0]);
        GLD16(gB[1] + koff, lB[1]);
        __syncthreads();

        bf16x8 af[4], bfr[4];
        #pragma unroll
        for (int m = 0; m < 4; ++m) af[m]  = *(const bf16x8*)(aptr + m * 16 * BKg);
        #pragma unroll
        for (int n = 0; n < 4; ++n) bfr[n] = *(const bf16x8*)(bptr + n * 16 * BKg);
        #pragma unroll
        for (int m = 0; m < 4; ++m)
            #pragma unroll
            for (int n = 0; n < 4; ++n)
                acc[m][n] = __builtin_amdgcn_mfma_f32_16x16x32_bf16(af[m], bfr[n], acc[m][n], 0, 0, 0);
        __syncthreads();
    }

    // C/D layout: col=lane&15, row=(lane>>4)*4+j
    const int crow0 = m0 + wm * 64 + ((lane >> 4) << 2);
    const int ccol0 = n0 + wn * 64 + (lane & 15);
    if (ATOMIC) {
        #pragma unroll
        for (int m = 0; m < 4; ++m)
            #pragma unroll
            for (int n = 0; n < 4; ++n) {
                const int col = ccol0 + n * 16;
                if (col < PCOL) {
                    float* orow = dst + (size_t)(crow0 + m * 16) * PCOL + col;
                    #pragma unroll
                    for (int j = 0; j < 4; ++j)
                        atomicAdd(orow + (size_t)j * PCOL, acc[m][n][j]);
                }
            }
    } else {
        float* pbase = dst + (size_t)bz * NB * NPAD;
        #pragma unroll
        for (int m = 0; m < 4; ++m)
            #pragma unroll
            for (int n = 0; n < 4; ++n) {
                float* prow = pbase + (size_t)(crow0 + m * 16) * NPAD + ccol0 + n * 16;
                #pragma unroll
                for (int j = 0; j < 4; ++j)
                    prow[(size_t)j * NPAD] = acc[m][n][j];
            }
    }
}

// ---------------------------------------------------------------------------
// Kernel R: out[b][p] = part0[b][p] + part1[b][p] + bt[p] + std[b]*(bl[p]+bh[p])
// one row per block; threads 0..179 each handle 4 consecutive p (16B aligned)
// ---------------------------------------------------------------------------
__global__ __launch_bounds__(192) void reduce_bias(const float* __restrict__ part,
                                                   const float* __restrict__ bt,
                                                   const float* __restrict__ bl,
                                                   const float* __restrict__ bh,
                                                   const float* __restrict__ stdv,
                                                   float* __restrict__ out) {
    const int b = blockIdx.x;
    const int p = threadIdx.x << 2;
    if (p >= PCOL) return;
    const float4 p0 = *(const float4*)(part + (size_t)b * NPAD + p);
    const float4 p1 = *(const float4*)(part + (size_t)NB * NPAD + (size_t)b * NPAD + p);
    const float s = stdv[b];
    const float4 vt = *(const float4*)(bt + p);
    const float4 vl = *(const float4*)(bl + p);
    const float4 vh = *(const float4*)(bh + p);
    float4 o;
    o.x = p0.x + p1.x + vt.x + s * (vl.x + vh.x);
    o.y = p0.y + p1.y + vt.y + s * (vl.y + vh.y);
    o.z = p0.z + p1.z + vt.z + s * (vl.z + vh.z);
    o.w = p0.w + p1.w + vt.w + s * (vl.w + vh.w);
    *(float4*)(out + (size_t)b * PCOL + p) = o;
}

// ---------------------------------------------------------------------------
extern "C" void kernel_launch(void* const* d_in, const int* in_sizes, int n_in,
                              void* d_out, int out_size, void* d_ws, size_t ws_size,
                              hipStream_t stream) {
    (void)in_sizes; (void)n_in; (void)out_size;
    if (ws_size < WS_MIN) return;

    const float* x  = (const float*)d_in[0];
    const float* Wt = (const float*)d_in[1];
    const float* bt = (const float*)d_in[2];
    const float* Wl = (const float*)d_in[3];
    const float* bl = (const float*)d_in[4];
    const float* Wh = (const float*)d_in[5];
    const float* bh = (const float*)d_in[6];
    float* out = (float*)d_out;

    char* ws = (char*)d_ws;
    u16*   xbf  = (u16*)ws;
    u16*   Gm   = (u16*)(ws + WS_XBF_BYTES);
    float* sd   = (float*)(ws + WS_XBF_BYTES + WS_G_BYTES);
    float* part = (float*)(ws + WS_MIN);

    prep_rows<<<NB, 256, 0, stream>>>(x, xbf, sd);
    prep_weights<<<NPAD, 256, 0, stream>>>(Wt, Wl, Wh, Gm);

    if (ws_size >= WS_FULL) {
        gemm_splitk<0><<<768, 256, 0, stream>>>(xbf, Gm, part);
        reduce_bias<<<NB, 192, 0, stream>>>(part, bt, bl, bh, sd, out);
    } else {
        bias_init<<<dim3(3, NB), 256, 0, stream>>>(bt, bl, bh, sd, out);
        gemm_splitk<1><<<768, 256, 0, stream>>>(xbf, Gm, out);
    }
}

// Round 3
// 112.880 us; speedup vs baseline: 1.6081x; 1.4238x over previous
//
#include <hip/hip_runtime.h>

typedef unsigned short u16;
typedef unsigned int   u32;
typedef __attribute__((ext_vector_type(8))) short bf16x8;
typedef __attribute__((ext_vector_type(4))) float f32x4;

#define LROW 4096
#define NB   8192
#define PCOL 720
#define NPAD 768
#define HH   2048
#define INV_SQRT2F 0.70710678118654752440f

// ws layout: xbf | G | std
#define WS_XBF_BYTES ((size_t)67108864)           // 8192*4096*2
#define WS_G_BYTES   ((size_t)6291456)            // 768*4096*2
#define WS_MIN       (WS_XBF_BYTES + WS_G_BYTES + (size_t)NB * 4)

__device__ __forceinline__ u16 f2bf(float f) {
    union { float f; u32 u; } v; v.f = f;
    u32 r = v.u + 0x7FFFu + ((v.u >> 16) & 1u);
    return (u16)(r >> 16);
}

#define SWZ(i) ((i) ^ (((i) >> 5) & 31))

// ---------------------------------------------------------------------------
// Kernel P: per-row moving-average (via prefix sum), std (ddof=1), x -> bf16
// ---------------------------------------------------------------------------
__global__ __launch_bounds__(256) void prep_rows(const float* __restrict__ x,
                                                 u16* __restrict__ xbf,
                                                 float* __restrict__ stdv) {
    __shared__ float S[LROW];
    __shared__ float wred[4];
    __shared__ float ends[2];
    __shared__ float rred[8];
    const int tid = threadIdx.x;
    const int lane = tid & 63, wv = tid >> 6;
    const size_t b = blockIdx.x;

    const float4* xr4 = (const float4*)(x + b * LROW);
    float4 q0 = xr4[tid * 4 + 0], q1 = xr4[tid * 4 + 1];
    float4 q2 = xr4[tid * 4 + 2], q3 = xr4[tid * 4 + 3];
    float r[16];
    r[0]=q0.x; r[1]=q0.y; r[2]=q0.z; r[3]=q0.w;
    r[4]=q1.x; r[5]=q1.y; r[6]=q1.z; r[7]=q1.w;
    r[8]=q2.x; r[9]=q2.y; r[10]=q2.z; r[11]=q2.w;
    r[12]=q3.x; r[13]=q3.y; r[14]=q3.z; r[15]=q3.w;

    float ps[16];
    float a = 0.f;
    #pragma unroll
    for (int k = 0; k < 16; ++k) { a += r[k]; ps[k] = a; }
    const float segsum = a;

    float v = segsum;
    #pragma unroll
    for (int off = 1; off < 64; off <<= 1) {
        float o = __shfl_up(v, off);
        if (lane >= off) v += o;
    }
    if (lane == 63) wred[wv] = v;
    if (tid == 0)   ends[0] = r[0];
    if (tid == 255) ends[1] = r[15];
    __syncthreads();

    float wbase = 0.f;
    #pragma unroll
    for (int w = 0; w < 4; ++w) if (w < wv) wbase += wred[w];
    const float ebase = wbase + v - segsum;

    #pragma unroll
    for (int k = 0; k < 16; ++k) {
        const int i = (tid << 4) + k;
        S[SWZ(i)] = ebase + ps[k];
    }
    __syncthreads();

    const float x0 = ends[0], xl = ends[1];
    float s1 = 0.f, s2 = 0.f;
    u16 ob[16];
    #pragma unroll
    for (int k = 0; k < 16; ++k) {
        const int i = (tid << 4) + k;
        int h = i + 12; h = h > LROW - 1 ? LROW - 1 : h;
        float wsum = S[SWZ(h)];
        if (i >= 13) wsum -= S[SWZ(i - 13)];
        if (i < 12) wsum += (float)(12 - i) * x0;
        if (i > LROW - 13) wsum += (float)(i - (LROW - 13)) * xl;
        const float xi = r[k];
        const float rr = xi - wsum * 0.04f;
        s1 += rr; s2 += rr * rr;
        ob[k] = f2bf(xi);
    }

    uint4 o0, o1;
    o0.x = (u32)ob[0]  | ((u32)ob[1]  << 16);
    o0.y = (u32)ob[2]  | ((u32)ob[3]  << 16);
    o0.z = (u32)ob[4]  | ((u32)ob[5]  << 16);
    o0.w = (u32)ob[6]  | ((u32)ob[7]  << 16);
    o1.x = (u32)ob[8]  | ((u32)ob[9]  << 16);
    o1.y = (u32)ob[10] | ((u32)ob[11] << 16);
    o1.z = (u32)ob[12] | ((u32)ob[13] << 16);
    o1.w = (u32)ob[14] | ((u32)ob[15] << 16);
    uint4* op = (uint4*)(xbf + b * LROW + ((size_t)tid << 4));
    op[0] = o0; op[1] = o1;

    #pragma unroll
    for (int off = 32; off; off >>= 1) {
        s1 += __shfl_down(s1, off);
        s2 += __shfl_down(s2, off);
    }
    if (lane == 0) { rred[wv * 2] = s1; rred[wv * 2 + 1] = s2; }
    __syncthreads();
    if (tid == 0) {
        const float S1 = rred[0] + rred[2] + rred[4] + rred[6];
        const float S2 = rred[1] + rred[3] + rred[5] + rred[7];
        const float mean = S1 / (float)LROW;
        float var = (S2 - (float)LROW * mean * mean) / (float)(LROW - 1);
        var = var < 0.f ? 0.f : var;
        stdv[b] = sqrtf(var) + 1e-5f;
    }
}

// ---------------------------------------------------------------------------
// Kernel W: fold weights into G[p][l] (bf16), rows 720..767 zero-padded.
// ---------------------------------------------------------------------------
__global__ __launch_bounds__(256) void prep_weights(const float* __restrict__ Wt,
                                                    const float* __restrict__ Wlo,
                                                    const float* __restrict__ Whi,
                                                    u16* __restrict__ Gm) {
    __shared__ float S[LROW];
    __shared__ float wred[4];
    __shared__ float sred[4];
    const int tid = threadIdx.x;
    const int lane = tid & 63, wv = tid >> 6;
    const int p = blockIdx.x;
    u16* grow = Gm + (size_t)p * LROW;
    if (p >= PCOL) {
        uint4 z; z.x = z.y = z.z = z.w = 0u;
        uint4* g4 = (uint4*)grow;
        for (int i = tid; i < LROW / 8; i += 256) g4[i] = z;
        return;
    }
    const float4* wt4 = (const float4*)(Wt + (size_t)p * LROW);
    float4 q0 = wt4[tid * 4 + 0], q1 = wt4[tid * 4 + 1];
    float4 q2 = wt4[tid * 4 + 2], q3 = wt4[tid * 4 + 3];
    const float4* lo4 = (const float4*)(Wlo + (size_t)p * HH);
    const float4* hi4 = (const float4*)(Whi + (size_t)p * HH);
    float4 a0 = lo4[tid * 2 + 0], a1 = lo4[tid * 2 + 1];
    float4 b0 = hi4[tid * 2 + 0], b1 = hi4[tid * 2 + 1];

    float w[16];
    w[0]=q0.x; w[1]=q0.y; w[2]=q0.z; w[3]=q0.w;
    w[4]=q1.x; w[5]=q1.y; w[6]=q1.z; w[7]=q1.w;
    w[8]=q2.x; w[9]=q2.y; w[10]=q2.z; w[11]=q2.w;
    w[12]=q3.x; w[13]=q3.y; w[14]=q3.z; w[15]=q3.w;
    float lv[8] = {a0.x,a0.y,a0.z,a0.w,a1.x,a1.y,a1.z,a1.w};
    float hv[8] = {b0.x,b0.y,b0.z,b0.w,b1.x,b1.y,b1.z,b1.w};

    float u[16], z_[16];
    float slo = 0.f;
    #pragma unroll
    for (int j = 0; j < 8; ++j) {
        u[2*j]   = (lv[j] + hv[j]) * INV_SQRT2F;
        u[2*j+1] = (lv[j] - hv[j]) * INV_SQRT2F;
        slo += lv[j];
    }
    #pragma unroll
    for (int k = 0; k < 16; ++k) z_[k] = w[k] - u[k];

    float ps[16];
    float a = 0.f;
    #pragma unroll
    for (int k = 0; k < 16; ++k) { a += z_[k]; ps[k] = a; }
    const float segsum = a;

    float v = segsum;
    #pragma unroll
    for (int off = 1; off < 64; off <<= 1) {
        float o = __shfl_up(v, off);
        if (lane >= off) v += o;
    }
    if (lane == 63) wred[wv] = v;
    #pragma unroll
    for (int off = 32; off; off >>= 1) slo += __shfl_down(slo, off);
    if (lane == 0) sred[wv] = slo;
    __syncthreads();

    float wbase = 0.f;
    #pragma unroll
    for (int ww = 0; ww < 4; ++ww) if (ww < wv) wbase += wred[ww];
    const float ebase = wbase + v - segsum;
    const float SLO = sred[0] + sred[1] + sred[2] + sred[3];

    #pragma unroll
    for (int k = 0; k < 16; ++k) {
        const int i = (tid << 4) + k;
        S[SWZ(i)] = ebase + ps[k];
    }
    __syncthreads();

    const float coef = -1.4142135623730951f * SLO / (float)LROW;
    u16 ob[16];
    #pragma unroll
    for (int k = 0; k < 16; ++k) {
        const int l = (tid << 4) + k;
        float zT;
        if (l == 0) {
            float acc = 0.f;
            for (int m = 0; m <= 12; ++m) acc += S[SWZ(m)];
            zT = acc * 0.04f;
        } else if (l == LROW - 1) {
            float acc = 0.f;
            for (int m = 0; m <= 12; ++m) acc += S[SWZ(LROW - 2 - m)];
            zT = (13.f * S[SWZ(LROW - 1)] - acc) * 0.04f;
        } else {
            int h = l + 12; h = h > LROW - 1 ? LROW - 1 : h;
            float t_ = S[SWZ(h)];
            if (l >= 13) t_ -= S[SWZ(l - 13)];
            zT = t_ * 0.04f;
        }
        float c;
        const int dmin = l < (LROW - 1 - l) ? l : (LROW - 1 - l);
        if (dmin >= 12)      c = 0.f;
        else if (dmin == 0)  c = -66.f / 25.f;
        else                 c = (float)(12 - dmin) * 0.04f;
        ob[k] = f2bf(zT + u[k] + coef * c);
    }

    uint4 o0, o1;
    o0.x = (u32)ob[0]  | ((u32)ob[1]  << 16);
    o0.y = (u32)ob[2]  | ((u32)ob[3]  << 16);
    o0.z = (u32)ob[4]  | ((u32)ob[5]  << 16);
    o0.w = (u32)ob[6]  | ((u32)ob[7]  << 16);
    o1.x = (u32)ob[8]  | ((u32)ob[9]  << 16);
    o1.y = (u32)ob[10] | ((u32)ob[11] << 16);
    o1.z = (u32)ob[12] | ((u32)ob[13] << 16);
    o1.w = (u32)ob[14] | ((u32)ob[15] << 16);
    uint4* op = (uint4*)(grow + ((size_t)tid << 4));
    op[0] = o0; op[1] = o1;
}

// ---------------------------------------------------------------------------
// Kernel G: fused GEMM  out[b][p] = sum_k xbf[b][k]*G[p][k] + bt[p] + std[b]*(bl[p]+bh[p])
// BM=128, BN=96, BK=32, grid 64x8=512 (exactly 2 blocks/CU), K=4096.
// 4-deep LDS multibuffer, ONE s_barrier per K-step, counted vmcnt (T3+T4),
// conflict-free XOR slot swizzle via pre-swizzled global source (T2/rule21),
// setprio around MFMA (T5). Bias folded into epilogue.
// ---------------------------------------------------------------------------
typedef __attribute__((address_space(1))) void gvoid;
typedef __attribute__((address_space(3))) void lvoid;
__device__ __forceinline__ void gld16(const void* g, void* l) {
    __builtin_amdgcn_global_load_lds((gvoid*)g, (lvoid*)l, 16, 0, 0);
}

#define TILE_B   14336        // (128+96)*32*2 bytes per buffer
#define NTILES   128          // K/BK

// wait own vmcnt: waves 0,1 have 4 loads/tile, waves 2,3 have 3
#define WAITVM(a, b) do { \
    if (wid < 2) asm volatile("s_waitcnt vmcnt(" #a ")" ::: "memory"); \
    else         asm volatile("s_waitcnt vmcnt(" #b ")" ::: "memory"); \
} while (0)

#define STAGE(T) do { \
    char* sb_ = smb + ((T) & 3) * TILE_B; \
    const size_t go_ = (size_t)(T) * 64; \
    gld16(g0 + go_, sb_ + lo0); \
    gld16(g1 + go_, sb_ + lo1); \
    gld16(g2 + go_, sb_ + lo2); \
    if (wid < 2) gld16(g3 + go_, sb_ + lo3); \
} while (0)

#define BODY(T, VMA, VMB, DOSTAGE) do { \
    WAITVM(VMA, VMB); \
    __builtin_amdgcn_s_barrier(); \
    __builtin_amdgcn_sched_barrier(0); \
    const char* sa_ = smb + ((T) & 3) * TILE_B; \
    bf16x8 af0 = *(const bf16x8*)(sa_ + aoff); \
    bf16x8 af1 = *(const bf16x8*)(sa_ + aoff + 1024); \
    bf16x8 af2 = *(const bf16x8*)(sa_ + aoff + 2048); \
    bf16x8 af3 = *(const bf16x8*)(sa_ + aoff + 3072); \
    bf16x8 bv0 = *(const bf16x8*)(sa_ + boff); \
    bf16x8 bv1 = *(const bf16x8*)(sa_ + boff + 1024); \
    bf16x8 bv2 = *(const bf16x8*)(sa_ + boff + 2048); \
    if (DOSTAGE) STAGE((T) + 3); \
    asm volatile("s_waitcnt lgkmcnt(0)" ::: "memory"); \
    __builtin_amdgcn_sched_barrier(0); \
    __builtin_amdgcn_s_setprio(1); \
    acc[0][0] = __builtin_amdgcn_mfma_f32_16x16x32_bf16(af0, bv0, acc[0][0], 0, 0, 0); \
    acc[0][1] = __builtin_amdgcn_mfma_f32_16x16x32_bf16(af0, bv1, acc[0][1], 0, 0, 0); \
    acc[0][2] = __builtin_amdgcn_mfma_f32_16x16x32_bf16(af0, bv2, acc[0][2], 0, 0, 0); \
    acc[1][0] = __builtin_amdgcn_mfma_f32_16x16x32_bf16(af1, bv0, acc[1][0], 0, 0, 0); \
    acc[1][1] = __builtin_amdgcn_mfma_f32_16x16x32_bf16(af1, bv1, acc[1][1], 0, 0, 0); \
    acc[1][2] = __builtin_amdgcn_mfma_f32_16x16x32_bf16(af1, bv2, acc[1][2], 0, 0, 0); \
    acc[2][0] = __builtin_amdgcn_mfma_f32_16x16x32_bf16(af2, bv0, acc[2][0], 0, 0, 0); \
    acc[2][1] = __builtin_amdgcn_mfma_f32_16x16x32_bf16(af2, bv1, acc[2][1], 0, 0, 0); \
    acc[2][2] = __builtin_amdgcn_mfma_f32_16x16x32_bf16(af2, bv2, acc[2][2], 0, 0, 0); \
    acc[3][0] = __builtin_amdgcn_mfma_f32_16x16x32_bf16(af3, bv0, acc[3][0], 0, 0, 0); \
    acc[3][1] = __builtin_amdgcn_mfma_f32_16x16x32_bf16(af3, bv1, acc[3][1], 0, 0, 0); \
    acc[3][2] = __builtin_amdgcn_mfma_f32_16x16x32_bf16(af3, bv2, acc[3][2], 0, 0, 0); \
    __builtin_amdgcn_s_setprio(0); \
} while (0)

__global__ __launch_bounds__(256, 2) void gemm_fused(const u16* __restrict__ Abf,
                                                     const u16* __restrict__ Gbf,
                                                     const float* __restrict__ bt,
                                                     const float* __restrict__ bl,
                                                     const float* __restrict__ bh,
                                                     const float* __restrict__ stdv,
                                                     float* __restrict__ out) {
    __shared__ __align__(16) char Sm[4 * TILE_B];   // 57344 B
    char* smb = (char*)Sm;
    const int tid = threadIdx.x;
    const int l = tid & 63, wid = tid >> 6;

    // XCD-chunked swizzle: 512 = 8 XCDs x 64; n fastest within chunk
    const int orig = blockIdx.x;
    const int chunk = orig & 7, pos = orig >> 3;
    const int bx = pos & 7;                 // n-tile 0..7
    const int by = (chunk << 3) + (pos >> 3);  // m-tile 0..63
    const int m0 = by * 128;
    const int n0 = bx * 96;

    // ---- staging descriptors (pre-swizzled global source, rule #21) ----
    // stage instr covers 16 rows; lane l -> row +(l>>2), slot (l&3);
    // source slot = (l&3) ^ ((l>>3)&3)  ==> LDS(row,slot)=G(row, slot^((row>>1)&3))
    const int sgb = (((l & 3) ^ ((l >> 3) & 3)) << 4);   // byte within row
    const int rsub = l >> 2;
    const char* gmat = (wid < 2) ? (const char*)Abf : (const char*)Gbf;
    const int row00 = (wid < 2) ? (m0 + wid * 64) : (n0 + (wid - 2) * 48);
    const int lob   = (wid < 2) ? (wid * 4096) : (8192 + (wid - 2) * 3072);
    const char* g0 = gmat + (((size_t)(row00 +  0 + rsub)) << 13) + sgb;
    const char* g1 = gmat + (((size_t)(row00 + 16 + rsub)) << 13) + sgb;
    const char* g2 = gmat + (((size_t)(row00 + 32 + rsub)) << 13) + sgb;
    const char* g3 = gmat + (((size_t)(row00 + 48 + rsub)) << 13) + sgb;
    const int lo0 = lob, lo1 = lob + 1024, lo2 = lob + 2048, lo3 = lob + 3072;

    // ---- read offsets (swizzled): slot' = (l>>4) ^ ((row>>1)&3) ----
    const int wm = wid >> 1, wn = wid & 1;
    const int soff = (((l >> 4) ^ ((l >> 1) & 3)) << 4);
    const int aoff = (wm * 64 + (l & 15)) * 64 + soff;
    const int boff = 8192 + (wn * 48 + (l & 15)) * 64 + soff;

    f32x4 acc[4][3] = {};

    STAGE(0); STAGE(1); STAGE(2);

    for (int t = 0; t < NTILES - 3; ++t) {
        BODY(t, 8, 6, 1);
    }
    BODY(NTILES - 3, 8, 6, 0);
    BODY(NTILES - 2, 4, 3, 0);
    BODY(NTILES - 1, 0, 0, 0);

    // ---- epilogue: out = acc + bt + std*(bl+bh) ----
    const int crow = m0 + wm * 64 + ((l >> 4) << 2);   // + m*16 + j
    const int ccol = n0 + wn * 48 + (l & 15);          // + n*16
    float btv[3], bsv[3];
    #pragma unroll
    for (int n = 0; n < 3; ++n) {
        const int col = ccol + n * 16;
        if (col < PCOL) { btv[n] = bt[col]; bsv[n] = bl[col] + bh[col]; }
        else            { btv[n] = 0.f; bsv[n] = 0.f; }
    }
    #pragma unroll
    for (int m = 0; m < 4; ++m) {
        const int row = crow + m * 16;
        const float4 sv = *(const float4*)(stdv + row);
        #pragma unroll
        for (int n = 0; n < 3; ++n) {
            const int col = ccol + n * 16;
            if (col < PCOL) {
                float* orow = out + (size_t)row * PCOL + col;
                #pragma unroll
                for (int j = 0; j < 4; ++j) {
                    const float s = (j == 0) ? sv.x : (j == 1) ? sv.y : (j == 2) ? sv.z : sv.w;
                    orow[(size_t)j * PCOL] = acc[m][n][j] + btv[n] + s * bsv[n];
                }
            }
        }
    }
}

// ---------------------------------------------------------------------------
extern "C" void kernel_launch(void* const* d_in, const int* in_sizes, int n_in,
                              void* d_out, int out_size, void* d_ws, size_t ws_size,
                              hipStream_t stream) {
    (void)in_sizes; (void)n_in; (void)out_size;
    if (ws_size < WS_MIN) return;

    const float* x  = (const float*)d_in[0];
    const float* Wt = (const float*)d_in[1];
    const float* bt = (const float*)d_in[2];
    const float* Wl = (const float*)d_in[3];
    const float* bl = (const float*)d_in[4];
    const float* Wh = (const float*)d_in[5];
    const float* bh = (const float*)d_in[6];
    float* out = (float*)d_out;

    char* ws = (char*)d_ws;
    u16*   xbf = (u16*)ws;
    u16*   Gm  = (u16*)(ws + WS_XBF_BYTES);
    float* sd  = (float*)(ws + WS_XBF_BYTES + WS_G_BYTES);

    prep_rows<<<NB, 256, 0, stream>>>(x, xbf, sd);
    prep_weights<<<NPAD, 256, 0, stream>>>(Wt, Wl, Wh, Gm);
    gemm_fused<<<512, 256, 0, stream>>>(xbf, Gm, bt, bl, bh, sd, out);
}